// Round 6
// baseline (74.765 us; speedup 1.0000x reference)
//
#include <hip/hip_runtime.h>
#include <hip/hip_bf16.h>

#define LOG2E 1.4426950408889634f
#define SC2   2.8853900817779268f   // 2*log2(e)

typedef __attribute__((ext_vector_type(8))) short short8b;   // 8 bf16 (4 VGPR)
typedef __attribute__((ext_vector_type(4))) short short4b;   // 4 bf16 (8 B)
typedef __attribute__((ext_vector_type(4))) float f32x4;

__device__ __forceinline__ float fast_exp2(float x) {
#if __has_builtin(__builtin_amdgcn_exp2f)
  return __builtin_amdgcn_exp2f(x);
#else
  return exp2f(x);
#endif
}
__device__ __forceinline__ float fast_rcp(float x) {
#if __has_builtin(__builtin_amdgcn_rcpf)
  return __builtin_amdgcn_rcpf(x);
#else
  return 1.0f / x;
#endif
}
__device__ __forceinline__ short f2bf(float f) {
  __hip_bfloat16 h = __float2bfloat16(f);
  return *reinterpret_cast<short*>(&h);
}

// ---------------------------------------------------------------------------
// Stage 1: O = relu(X @ W^T + bias) via bf16 MFMA (f32 accumulate).
// Tile 128x64, 4 waves (2x2), per-wave 64x32 = 4x2 frags of 16x16.
// ---------------------------------------------------------------------------
__global__ __launch_bounds__(256) void gemm_mfma_kernel(
    const float* __restrict__ Xa, const float* __restrict__ Wa,
    const float* __restrict__ ba, float* __restrict__ Oa,
    const float* __restrict__ Xb, const float* __restrict__ Wb,
    const float* __restrict__ bb, float* __restrict__ Ob) {
  const float* X = blockIdx.z ? Xb : Xa;
  const float* W = blockIdx.z ? Wb : Wa;
  const float* bias = blockIdx.z ? bb : ba;
  float* O = blockIdx.z ? Ob : Oa;

  __shared__ __align__(16) short As[128 * 40];  // 128 rows x 32 bf16 (+8 pad)
  __shared__ __align__(16) short Ws[64 * 40];

  int t = threadIdx.x;
  int m0 = blockIdx.x * 128, n0 = blockIdx.y * 64;
  int l = t & 63, w = t >> 6;
  int wm = (w >> 1) * 64, wn = (w & 1) * 32;
  int lr = l & 15, ko = (l >> 4) * 8;

  f32x4 acc[4][2];
#pragma unroll
  for (int m = 0; m < 4; ++m)
#pragma unroll
    for (int n = 0; n < 2; ++n) acc[m][n] = f32x4{0.f, 0.f, 0.f, 0.f};

  for (int k0 = 0; k0 < 512; k0 += 32) {
#pragma unroll
    for (int s = 0; s < 4; ++s) {
      int slot = t + s * 256;
      int row = slot >> 3, q = (slot & 7) << 2;
      float4 v = *reinterpret_cast<const float4*>(&X[(m0 + row) * 512 + k0 + q]);
      short4b sv = {f2bf(v.x), f2bf(v.y), f2bf(v.z), f2bf(v.w)};
      *reinterpret_cast<short4b*>(&As[row * 40 + q]) = sv;
    }
#pragma unroll
    for (int s = 0; s < 2; ++s) {
      int slot = t + s * 256;
      int row = slot >> 3, q = (slot & 7) << 2;
      float4 v = *reinterpret_cast<const float4*>(&W[(n0 + row) * 512 + k0 + q]);
      short4b sv = {f2bf(v.x), f2bf(v.y), f2bf(v.z), f2bf(v.w)};
      *reinterpret_cast<short4b*>(&Ws[row * 40 + q]) = sv;
    }
    __syncthreads();

    short8b afr[4], bfr[2];
#pragma unroll
    for (int m = 0; m < 4; ++m)
      afr[m] = *reinterpret_cast<const short8b*>(&As[(wm + m * 16 + lr) * 40 + ko]);
#pragma unroll
    for (int n = 0; n < 2; ++n)
      bfr[n] = *reinterpret_cast<const short8b*>(&Ws[(wn + n * 16 + lr) * 40 + ko]);
#pragma unroll
    for (int m = 0; m < 4; ++m)
#pragma unroll
      for (int n = 0; n < 2; ++n)
        acc[m][n] = __builtin_amdgcn_mfma_f32_16x16x32_bf16(afr[m], bfr[n], acc[m][n], 0, 0, 0);
    __syncthreads();
  }

#pragma unroll
  for (int n = 0; n < 2; ++n) {
    int col = n0 + wn + n * 16 + lr;
    float bv = bias[col];
#pragma unroll
    for (int m = 0; m < 4; ++m) {
      int rbase = m0 + wm + m * 16 + (l >> 4) * 4;
#pragma unroll
      for (int r = 0; r < 4; ++r) {
        float v = acc[m][n][r] + bv;
        O[(rbase + r) * 512 + col] = v > 0.f ? v : 0.f;
      }
    }
  }
}

// ---------------------------------------------------------------------------
// Stage 1.5: per (bh, jblk, group-of-8-j) compact nonzero B entries into an
// INTERLEAVED layout entry[s][jj] (jj = j&7), zero-padded to the group's max
// count (rounded up to even).  Pair = (B*2log2e, qm) with qm = -2*q[c] whose
// low 8 mantissa bits are replaced by c<<2 (byte offset; rel perturb 3e-5).
// Zero entries contribute exactly 0 through the paired-rcp formula.
// Also emits Kj = sum_{nz} q_c per j.  One wave == one group of 8 j's.
// ---------------------------------------------------------------------------
__global__ __launch_bounds__(256) void compact_kernel(
    const float* __restrict__ Br, const float* __restrict__ q,
    float2* __restrict__ Cb, unsigned* __restrict__ Cnt, float* __restrict__ Ksum) {
  int blk = blockIdx.x;
  int bh = blk >> 3, jblk = blk & 7;
  int t = threadIdx.x;
  int jl = t >> 3, p = t & 7;     // j-in-block 0..31, scanner 0..7
  int g = t >> 6, jj = jl & 7;    // group (==wave) 0..3, j-in-group
  __shared__ float Bls[32][65];
  __shared__ float qls[64];

  const float* Bbase = Br + bh * 16384 + jblk * 2048;
#pragma unroll
  for (int it = 0; it < 2; ++it) {
    int idx = it * 256 + t;           // 512 float4 slots: 32 rows x 16 quads
    int row = idx >> 4, c4 = (idx & 15) << 2;
    float4 v = *reinterpret_cast<const float4*>(&Bbase[row * 64 + c4]);
    Bls[row][c4 + 0] = v.x; Bls[row][c4 + 1] = v.y;
    Bls[row][c4 + 2] = v.z; Bls[row][c4 + 3] = v.w;
  }
  if (t < 64) qls[t] = q[t];
  __syncthreads();

  int c0 = p * 8;
  // pass 1: count + K
  int nz = 0;
  float K = 0.f;
#pragma unroll
  for (int cc = 0; cc < 8; ++cc) {
    float v = Bls[jl][c0 + cc];
    if (v > 0.f) { ++nz; K += qls[c0 + cc]; }
  }
  // width-8 inclusive prefix over scanners
  int incl = nz;
#pragma unroll
  for (int d = 1; d < 8; d <<= 1) {
    int u = __shfl_up(incl, d, 8);
    if (p >= d) incl += u;
  }
  int off = incl - nz;
  int total = __shfl(incl, 7, 8);   // this j's count (uniform over its 8 scanners)

  // group (wave) max count, rounded to even
  int maxc = total;
#pragma unroll
  for (int d = 8; d < 64; d <<= 1) maxc = max(maxc, __shfl_xor(maxc, d));
  maxc = (maxc + 1) & ~1;

  // pass 2: write interleaved entries
  float2* dst = Cb + (size_t)(((bh * 8 + jblk) * 4 + g) * 64) * 8;
  int k = off;
#pragma unroll
  for (int cc = 0; cc < 8; ++cc) {
    int c = c0 + cc;
    float v = Bls[jl][c];
    if (v > 0.f) {
      unsigned qb = (__float_as_uint(-2.f * qls[c]) & ~255u) | (unsigned)(c << 2);
      dst[k * 8 + jj] = make_float2(v * SC2, __uint_as_float(qb));
      ++k;
    }
  }
  // zero-fill padding s in [total, maxc)
  for (int s = total + p; s < maxc; s += 8) dst[s * 8 + jj] = make_float2(0.f, 0.f);

  // K reduce over the 8 scanners
#pragma unroll
  for (int d = 1; d < 8; d <<= 1) K += __shfl_xor(K, d, 8);
  if (p == 0) Ksum[bh * 256 + jblk * 32 + jl] = K;
  if ((t & 63) == 0) Cnt[(bh * 8 + jblk) * 4 + g] = (unsigned)maxc;
}

// ---------------------------------------------------------------------------
// Stage 2 (sparse, interleaved): per wave, all 8 j-lists advance together in
// one fixed-bound loop (16 evals/iter = 2 s-steps x 8 jj), rcp-paired across
// the two s-steps within the same jj (per-j accumulators stay separate).
// Pair data is wave-uniform -> scalar loads.  A staged [i][c] pad-65.
// grid (64 bh, 8 jblk, 2 isplit); 512 threads; g=t>>7 owns 8 j's, il=t&127.
// ---------------------------------------------------------------------------
#define PAIR(b0, q0, b1, q1, ACCJ) {                                        \
    float a0 = *(const float*)(AlsB + (__float_as_uint(q0) & 255u));        \
    float a1 = *(const float*)(AlsB + (__float_as_uint(q1) & 255u));        \
    float e0 = fast_exp2(fminf(a0 * (b0), 60.f));                           \
    float e1 = fast_exp2(fminf(a1 * (b1), 60.f));                           \
    float u0 = e0 + 1.f, u1 = e1 + 1.f;                                     \
    float nn = fmaf((q0), u1, (q1) * u0);                                   \
    ACCJ = fmaf(nn, fast_rcp(u0 * u1), ACCJ); }

__global__ __launch_bounds__(512, 6) void attmap_kernel(
    const float* __restrict__ Ar, const float2* __restrict__ Cb,
    const unsigned* __restrict__ Cnt,
    float* __restrict__ rowpart, float* __restrict__ colsum) {
  int bh = blockIdx.x, jblk = blockIdx.y, isplit = blockIdx.z;
  int t = threadIdx.x;
  int il = t & 127;
  int g = __builtin_amdgcn_readfirstlane(t >> 7);  // wave-uniform group id
  __shared__ __align__(16) float Als[128 * 65];
  __shared__ float red[512];
  __shared__ float cpart[8][8];

  const float* Abase = Ar + bh * 16384 + isplit * 8192;
#pragma unroll
  for (int it = 0; it < 4; ++it) {
    int idx = it * 512 + t;           // float4 slot: 128 i x 16 quads
    int r = idx >> 4, c4 = (idx & 15) << 2;
    float4 v = *reinterpret_cast<const float4*>(&Abase[r * 64 + c4]);
    Als[r * 65 + c4 + 0] = v.x; Als[r * 65 + c4 + 1] = v.y;
    Als[r * 65 + c4 + 2] = v.z; Als[r * 65 + c4 + 3] = v.w;
  }
  __syncthreads();

  const char* AlsB = (const char*)(&Als[il * 65]);
  float acc[8];
#pragma unroll
  for (int jj = 0; jj < 8; ++jj) acc[jj] = 0.f;

  int gi = (bh * 8 + jblk) * 4 + g;
  int n = (int)__builtin_amdgcn_readfirstlane(Cnt[gi]);  // even
  const float4* P4 = reinterpret_cast<const float4*>(Cb + (size_t)gi * 512);

#pragma unroll 1
  for (int s = 0; s < n; s += 2) {
    const float4* S0 = P4 + s * 4;   // wave-uniform -> s_load
    float4 x0 = S0[0], x1 = S0[1], x2 = S0[2], x3 = S0[3];  // step s
    float4 y0 = S0[4], y1 = S0[5], y2 = S0[6], y3 = S0[7];  // step s+1
    PAIR(x0.x, x0.y, y0.x, y0.y, acc[0]);
    PAIR(x0.z, x0.w, y0.z, y0.w, acc[1]);
    PAIR(x1.x, x1.y, y1.x, y1.y, acc[2]);
    PAIR(x1.z, x1.w, y1.z, y1.w, acc[3]);
    PAIR(x2.x, x2.y, y2.x, y2.y, acc[4]);
    PAIR(x2.z, x2.w, y2.z, y2.w, acc[5]);
    PAIR(x3.x, x3.y, y3.x, y3.y, acc[6]);
    PAIR(x3.z, x3.w, y3.z, y3.w, acc[7]);
  }

  float rs = 0.f;
#pragma unroll
  for (int jj = 0; jj < 8; ++jj) rs += acc[jj];
  red[t] = rs;

  int lane = t & 63, w = t >> 6;
#pragma unroll
  for (int jj = 0; jj < 8; ++jj) {
    float v = acc[jj];
#pragma unroll
    for (int off = 32; off >= 1; off >>= 1) v += __shfl_xor(v, off);
    if (lane == 0) cpart[w][jj] = v;
  }
  __syncthreads();
  if (t < 128) {
    rowpart[(bh * 8 + jblk) * 256 + isplit * 128 + t] =
        red[t] + red[t + 128] + red[t + 256] + red[t + 384];
  } else if (t < 160) {
    int jl = t - 128;
    int gg = jl >> 3, jj = jl & 7;
    colsum[(bh * 2 + isplit) * 256 + jblk * 32 + jl] =
        cpart[2 * gg][jj] + cpart[2 * gg + 1][jj];
  }
}

// ---------------------------------------------------------------------------
// Stage 3: per (bh): softmax over 256 row/col means (+Kj shift on cols),
// temps to ws, pooled outputs into out[0:8192].  512 threads.
// ---------------------------------------------------------------------------
__global__ __launch_bounds__(512) void softmax_pool_kernel(
    const float* __restrict__ rowpart, const float* __restrict__ colsum,
    const float* __restrict__ Ksum,
    const float* __restrict__ A0, const float* __restrict__ B0,
    float* __restrict__ b2a, float* __restrict__ a2b, float* __restrict__ out) {
  int bh = blockIdx.x;
  int b = bh >> 3, h = bh & 7;
  int t = threadIdx.x;
  int tt = t & 255;
  int lane = t & 63, w = (t >> 6) & 3;
  __shared__ float redA[4], redB[4], redC[4], redD[4];
  __shared__ float tA[256], tB[256];
  __shared__ float pp[8][64];

  float r = 0.f;
#pragma unroll
  for (int jb = 0; jb < 8; ++jb) r += rowpart[(bh * 8 + jb) * 256 + tt];
  r *= (1.f / 256.f);
  float cs = Ksum[bh * 256 + tt] +
             (colsum[(bh * 2 + 0) * 256 + tt] + colsum[(bh * 2 + 1) * 256 + tt]) * (1.f / 256.f);

  float mr = r, mc = cs;
#pragma unroll
  for (int off = 32; off >= 1; off >>= 1) {
    mr = fmaxf(mr, __shfl_xor(mr, off));
    mc = fmaxf(mc, __shfl_xor(mc, off));
  }
  if (lane == 0) { redA[w] = mr; redB[w] = mc; }
  __syncthreads();
  mr = fmaxf(fmaxf(redA[0], redA[1]), fmaxf(redA[2], redA[3]));
  mc = fmaxf(fmaxf(redB[0], redB[1]), fmaxf(redB[2], redB[3]));

  float er = fast_exp2((r - mr) * LOG2E);
  float ec = fast_exp2((cs - mc) * LOG2E);
  float sr = er, sc = ec;
#pragma unroll
  for (int off = 32; off >= 1; off >>= 1) {
    sr += __shfl_xor(sr, off);
    sc += __shfl_xor(sc, off);
  }
  if (lane == 0) { redC[w] = sr; redD[w] = sc; }
  __syncthreads();
  sr = redC[0] + redC[1] + redC[2] + redC[3];
  sc = redD[0] + redD[1] + redD[2] + redD[3];

  float vb2a = er * fast_rcp(sr);
  float va2b = ec * fast_rcp(sc);
  tA[tt] = vb2a; tB[tt] = va2b;
  b2a[bh * 256 + tt] = vb2a;
  a2b[bh * 256 + tt] = va2b;
  __syncthreads();

  int c = t & 63, iq = t >> 6;  // 8 groups x 32 i
  const float* Ab = A0 + b * 131072 + h * 16384;
  const float* Bb = B0 + b * 131072 + h * 16384;
  float pa = 0.f, pb = 0.f;
#pragma unroll 4
  for (int ii = 0; ii < 32; ++ii) {
    int i = (iq << 5) + ii;
    pa = fmaf(Ab[i * 64 + c], tA[i], pa);
    pb = fmaf(Bb[i * 64 + c], tB[i], pb);
  }
  pp[iq][c] = pa;
  __syncthreads();
  if (t < 64) {
    float s = 0.f;
#pragma unroll
    for (int k = 0; k < 8; ++k) s += pp[k][t];
    out[b * 1024 + h * 64 + t] = s;
  }
  __syncthreads();
  pp[iq][c] = pb;
  __syncthreads();
  if (t < 64) {
    float s = 0.f;
#pragma unroll
    for (int k = 0; k < 8; ++k) s += pp[k][t];
    out[b * 1024 + 512 + h * 64 + t] = s;
  }
}

// ---------------------------------------------------------------------------
// Stage 4: out1[b,i] = mean_h temp_b2a ; out2[b,j] = mean_h temp_a2b
// ---------------------------------------------------------------------------
__global__ __launch_bounds__(256) void mean_heads_kernel(
    const float* __restrict__ b2a, const float* __restrict__ a2b,
    float* __restrict__ out) {
  int b = blockIdx.x, t = threadIdx.x;
  float s1 = 0.f, s2 = 0.f;
#pragma unroll
  for (int h = 0; h < 8; ++h) {
    s1 += b2a[(b * 8 + h) * 256 + t];
    s2 += a2b[(b * 8 + h) * 256 + t];
  }
  out[8192 + b * 256 + t] = s1 * 0.125f;
  out[10240 + b * 256 + t] = s2 * 0.125f;
}

extern "C" void kernel_launch(void* const* d_in, const int* in_sizes, int n_in,
                              void* d_out, int out_size, void* d_ws, size_t ws_size,
                              hipStream_t stream) {
  const float* A  = (const float*)d_in[0];
  const float* B  = (const float*)d_in[1];
  const float* W1 = (const float*)d_in[2];
  const float* b1 = (const float*)d_in[3];
  const float* W2 = (const float*)d_in[4];
  const float* b2 = (const float*)d_in[5];
  const float* q  = (const float*)d_in[6];
  float* out = (float*)d_out;
  float* ws = (float*)d_ws;

  float*    Ar      = ws;                          // 1,048,576 f
  float*    Brr     = ws + 1048576;                // 1,048,576 f
  float2*   Cb      = (float2*)(ws + 2097152);     // 1,048,576 f2 (8 MB)
  unsigned* Cnt     = (unsigned*)(ws + 4194304);   // 2,048 u32
  float*    Ksum    = ws + 4210688;                // 16,384 f
  float*    rowpart = ws + 4227072;                // 131,072 f
  float*    colsum  = ws + 4358144;                // 32,768 f  (end ~17.6 MB)
  float*    b2a     = ws;                          // alias Ar (dead after attmap)
  float*    a2b     = ws + 16384;

  gemm_mfma_kernel<<<dim3(16, 8, 2), 256, 0, stream>>>(A, W1, b1, Ar, B, W2, b2, Brr);
  compact_kernel<<<512, 256, 0, stream>>>(Brr, q, Cb, Cnt, Ksum);
  attmap_kernel<<<dim3(64, 8, 2), 512, 0, stream>>>(Ar, Cb, Cnt, rowpart, colsum);
  softmax_pool_kernel<<<64, 512, 0, stream>>>(rowpart, colsum, Ksum, A, B, b2a, a2b, out);
  mean_heads_kernel<<<8, 256, 0, stream>>>(b2a, a2b, out);
}